// Round 19
// baseline (202.182 us; speedup 1.0000x reference)
//
#include <hip/hip_runtime.h>
#include <stdint.h>

typedef __bf16 bf16x8 __attribute__((ext_vector_type(8)));
typedef __bf16 bf16x2 __attribute__((ext_vector_type(2)));
typedef float  f32x4  __attribute__((ext_vector_type(4)));

__device__ inline unsigned short f2b(float f) {
  unsigned int u = __builtin_bit_cast(unsigned int, f);
  u += 0x7FFFu + ((u >> 16) & 1u);
  return (unsigned short)(u >> 16);
}
__device__ inline float b2f(unsigned short h) {
  unsigned int u = ((unsigned int)h) << 16;
  return __builtin_bit_cast(float, u);
}
__device__ inline unsigned int pkcvt(float a, float b) {
  bf16x2 t;
  t[0] = (__bf16)a;
  t[1] = (__bf16)b;
  return __builtin_bit_cast(unsigned int, t);
}
__device__ inline void gload_lds16(const void* g, void* l) {
  __builtin_amdgcn_global_load_lds(
      (const __attribute__((address_space(1))) unsigned int*)g,
      (__attribute__((address_space(3))) unsigned int*)l, 16, 0, 0);
}

// ---------------- prep: z=0 Wq|Wk|Wv transpose, z=1 Wo transpose, z=2 x cvt ----------------
__global__ void k_prep(const float* __restrict__ Wq, const float* __restrict__ Wk,
                       const float* __restrict__ Wv, const float* __restrict__ Wo,
                       const float* __restrict__ x, unsigned short* __restrict__ xb,
                       unsigned short* __restrict__ dstQKV, unsigned short* __restrict__ dstO,
                       int n4) {
  if (blockIdx.z == 2) {
    int nblk = gridDim.x * gridDim.y;
    int bid = blockIdx.y * gridDim.x + blockIdx.x;
    for (int i = bid * 256 + threadIdx.x; i < n4; i += nblk * 256) {
      float4 v = ((const float4*)x)[i];
      ushort4 o;
      o.x = f2b(v.x); o.y = f2b(v.y); o.z = f2b(v.z); o.w = f2b(v.w);
      ((ushort4*)xb)[i] = o;
    }
    return;
  }
  __shared__ float tile[32][33];
  int n0 = blockIdx.x * 32;
  int k0 = blockIdx.y * 32;
  const float* src; int ldn, noff, K;
  unsigned short* dst;
  if (blockIdx.z == 0) {
    K = 2048; dst = dstQKV;
    if (n0 < 2048)       { src = Wq; ldn = 2048; noff = n0; }
    else if (n0 < 2176)  { src = Wk; ldn = 128;  noff = n0 - 2048; }
    else                 { src = Wv; ldn = 128;  noff = n0 - 2176; }
  } else {
    if (n0 >= 2048) return;
    K = 2048; dst = dstO;
    src = Wo; ldn = 2048; noff = n0;
  }
  int tx = threadIdx.x & 31, ty = threadIdx.x >> 5;
  for (int yy = ty; yy < 32; yy += 8)
    tile[yy][tx] = src[(size_t)(k0 + yy) * ldn + noff + tx];
  __syncthreads();
  for (int yy = ty; yy < 32; yy += 8)
    dst[(size_t)(n0 + yy) * K + k0 + tx] = f2b(tile[tx][yy]);
}

// ---------------- bf16 GEMM, 128x96 tile (GEMM1: balanced 768 = 3/CU) ----------------
template<int BIAS3>
__global__ __launch_bounds__(256)
void k_gemm96(const unsigned short* __restrict__ A, const unsigned short* __restrict__ Bt,
              const float* __restrict__ b0, const float* __restrict__ b1,
              const float* __restrict__ b2, unsigned short* __restrict__ Cout,
              int M, int N, int K) {
  __shared__ unsigned short As[3][4096];   // 128x32
  __shared__ unsigned short Bs[3][3072];   // 96x32
  const int tid  = threadIdx.x;
  const int lane = tid & 63, wid = tid >> 6;
  const int lr = lane & 15, lk = lane >> 4;
  const int wr = wid >> 1,  wc = wid & 1;

  const int nwg = gridDim.x * gridDim.y;
  const int flat = blockIdx.y * gridDim.x + blockIdx.x;
  const int swz = (flat & 7) * (nwg >> 3) + (flat >> 3);
  const int mb = (swz / gridDim.x) * 128;
  const int nb = (swz % gridDim.x) * 96;

  const int srow = tid >> 2, scb = (tid & 3) * 8;
  const size_t gA = (size_t)(mb + srow) * K + scb;
  const int brow0 = wid * 32 + (lane >> 2);
  const int bcol  = (lane & 3) * 8;
  const size_t gB = (size_t)(nb + brow0) * K + bcol;
  const int bdst0 = (wid * 128 + lane) * 16;

  f32x4 acc[4][3];
  #pragma unroll
  for (int i = 0; i < 4; ++i)
    #pragma unroll
    for (int j = 0; j < 3; ++j) acc[i][j] = (f32x4){0.f, 0.f, 0.f, 0.f};

  auto stage = [&](int buf, int kt) {
    const size_t ko = (size_t)kt * 32;
    gload_lds16(A + gA + ko,                  &As[buf][(tid) * 8]);
    gload_lds16(A + gA + 64 * (size_t)K + ko, &As[buf][2048 + tid * 8]);
    if (wid < 3) {
      gload_lds16(Bt + gB + ko,                  (char*)&Bs[buf][0] + bdst0);
      gload_lds16(Bt + gB + 16 * (size_t)K + ko, (char*)&Bs[buf][0] + bdst0 + 1024);
    }
  };

  const int ktn = K >> 5;
  stage(0, 0);
  stage(1, 1);

  int cur = 0;
  #pragma unroll 1
  for (int kt = 0; kt < ktn; ++kt) {
    if (kt + 2 < ktn) {
      int nbuf = cur + 2; if (nbuf >= 3) nbuf -= 3;
      stage(nbuf, kt + 2);
      if (wid < 3) asm volatile("s_waitcnt vmcnt(8)" ::: "memory");
      else         asm volatile("s_waitcnt vmcnt(4)" ::: "memory");
    } else if (kt + 1 < ktn) {
      if (wid < 3) asm volatile("s_waitcnt vmcnt(4)" ::: "memory");
      else         asm volatile("s_waitcnt vmcnt(2)" ::: "memory");
    } else {
      asm volatile("s_waitcnt vmcnt(0)" ::: "memory");
    }
    __builtin_amdgcn_sched_barrier(0);
    __builtin_amdgcn_s_barrier();
    bf16x8 af[4], bfv[3];
    #pragma unroll
    for (int m = 0; m < 4; ++m)
      af[m]  = *(const bf16x8*)&As[cur][(wr * 64 + m * 16 + lr) * 32 + lk * 8];
    #pragma unroll
    for (int n = 0; n < 3; ++n)
      bfv[n] = *(const bf16x8*)&Bs[cur][(wc * 48 + n * 16 + lr) * 32 + lk * 8];
    #pragma unroll
    for (int m = 0; m < 4; ++m)
      #pragma unroll
      for (int n = 0; n < 3; ++n)
        acc[m][n] = __builtin_amdgcn_mfma_f32_16x16x32_bf16(af[m], bfv[n], acc[m][n], 0, 0, 0);
    __builtin_amdgcn_s_barrier();
    ++cur; if (cur == 3) cur = 0;
  }

  const int r0 = mb + wr * 64, c0 = nb + wc * 48;
  #pragma unroll
  for (int m = 0; m < 4; ++m) {
    #pragma unroll
    for (int n = 0; n < 3; ++n) {
      int col = c0 + n * 16 + lr;
      float bb;
      if (BIAS3) bb = (col < 2048) ? b0[col] : (col < 2176 ? b1[col - 2048] : b2[col - 2176]);
      else       bb = b0[col];
      #pragma unroll
      for (int r = 0; r < 4; ++r) {
        int row = r0 + m * 16 + lk * 4 + r;
        Cout[(size_t)row * N + col] = f2b(acc[m][n][r] + bb);
      }
    }
  }
}

// ---------------- GEMM2: 128x64 tile, grid 1024 = 4/CU; f32 out ----------------
// Wave = 64x32 (acc[4][2]); ds_read 6 per 8 MFMA; LDS 12KB x 3-ring = 36KB.
// Staging 3 gloads/thread/stage -> counted vmcnt {6,3,0}. XCD swizzle.
__global__ __launch_bounds__(256)
void k_gemm2(const unsigned short* __restrict__ A, const unsigned short* __restrict__ Bt,
             const float* __restrict__ b0, float* __restrict__ Cout,
             int M, int N, int K) {
  __shared__ unsigned short As[3][4096];   // 128x32
  __shared__ unsigned short Bs[3][2048];   // 64x32
  const int tid  = threadIdx.x;
  const int lane = tid & 63, wid = tid >> 6;
  const int lr = lane & 15, lk = lane >> 4;
  const int wr = wid >> 1,  wc = wid & 1;

  const int nwg = gridDim.x * gridDim.y;
  const int flat = blockIdx.y * gridDim.x + blockIdx.x;
  const int swz = (flat & 7) * (nwg >> 3) + (flat >> 3);
  const int mb = (swz / gridDim.x) * 128;
  const int nb = (swz % gridDim.x) * 64;

  const int srow = tid >> 2, scb = (tid & 3) * 8;
  const size_t gA = (size_t)(mb + srow) * K + scb;
  const size_t gB = (size_t)(nb + srow) * K + scb;   // rows 0..63 only (srow<64 when tid<256/..)

  f32x4 acc[4][2];
  #pragma unroll
  for (int i = 0; i < 4; ++i)
    #pragma unroll
    for (int j = 0; j < 2; ++j) acc[i][j] = (f32x4){0.f, 0.f, 0.f, 0.f};

  auto stage = [&](int buf, int kt) {
    const size_t ko = (size_t)kt * 32;
    gload_lds16(A + gA + ko,                  &As[buf][tid * 8]);
    gload_lds16(A + gA + 64 * (size_t)K + ko, &As[buf][2048 + tid * 8]);
    // B: 64 rows; thread tid covers chunk tid if tid<256 -> row tid>>2 in 0..63
    gload_lds16(Bt + gB + ko, &Bs[buf][tid * 8]);
  };

  const int ktn = K >> 5;
  stage(0, 0);
  stage(1, 1);

  int cur = 0;
  #pragma unroll 1
  for (int kt = 0; kt < ktn; ++kt) {
    if (kt + 2 < ktn) {
      int nbuf = cur + 2; if (nbuf >= 3) nbuf -= 3;
      stage(nbuf, kt + 2);
      asm volatile("s_waitcnt vmcnt(6)" ::: "memory");   // tile kt done; kt+1,kt+2 in flight
    } else if (kt + 1 < ktn) {
      asm volatile("s_waitcnt vmcnt(3)" ::: "memory");
    } else {
      asm volatile("s_waitcnt vmcnt(0)" ::: "memory");
    }
    __builtin_amdgcn_sched_barrier(0);
    __builtin_amdgcn_s_barrier();
    bf16x8 af[4], bfv[2];
    #pragma unroll
    for (int m = 0; m < 4; ++m)
      af[m]  = *(const bf16x8*)&As[cur][(wr * 64 + m * 16 + lr) * 32 + lk * 8];
    #pragma unroll
    for (int n = 0; n < 2; ++n)
      bfv[n] = *(const bf16x8*)&Bs[cur][(wc * 32 + n * 16 + lr) * 32 + lk * 8];
    #pragma unroll
    for (int m = 0; m < 4; ++m)
      #pragma unroll
      for (int n = 0; n < 2; ++n)
        acc[m][n] = __builtin_amdgcn_mfma_f32_16x16x32_bf16(af[m], bfv[n], acc[m][n], 0, 0, 0);
    __builtin_amdgcn_s_barrier();
    ++cur; if (cur == 3) cur = 0;
  }

  const int r0 = mb + wr * 64, c0 = nb + wc * 32;
  #pragma unroll
  for (int m = 0; m < 4; ++m) {
    #pragma unroll
    for (int n = 0; n < 2; ++n) {
      int col = c0 + n * 16 + lr;
      float bb = b0[col];
      #pragma unroll
      for (int r = 0; r < 4; ++r) {
        int row = r0 + m * 16 + lk * 4 + r;
        Cout[(size_t)row * N + col] = acc[m][n][r] + bb;
      }
    }
  }
}

// ---------------- RoPE (q heads + k); q pre-scaled by 1/sqrt(D) ----------------
__global__ void k_rope(const unsigned short* __restrict__ qkv,
                       unsigned short* __restrict__ qr,
                       unsigned short* __restrict__ kr,
                       int S, int H) {
  int R = blockIdx.x * 4 + (threadIdx.x >> 6);
  int lane = threadIdx.x & 63;
  int per_b = S * (H + 1);
  int b = R / per_b;
  int rem = R - b * per_b;
  int s = rem / (H + 1);
  int j = rem - s * (H + 1);
  const unsigned short* src = qkv + (size_t)(b * S + s) * 2304 + (j < H ? j * 128 : 2048);
  float x1 = b2f(src[lane]);
  float x2 = b2f(src[lane + 64]);
  float invf = expf(-(float)lane * (9.210340371976184f / 64.0f));
  float ang = (float)s * invf;
  float c = cosf(ang), sn = sinf(ang);
  float o1 = x1 * c - x2 * sn;
  float o2 = x1 * sn + x2 * c;
  unsigned short* dst;
  if (j < H) {
    const float scale = 0.08838834764831845f;
    o1 *= scale; o2 *= scale;
    dst = qr + ((size_t)(b * H + j) * S + s) * 128;
  } else {
    dst = kr + ((size_t)(b * S) + s) * 128;
  }
  dst[lane]      = f2b(o1);
  dst[lane + 64] = f2b(o2);
}

// ---------------- V transpose ----------------
__global__ void k_vtrans(const unsigned short* __restrict__ qkv,
                         unsigned short* __restrict__ vt, int S) {
  __shared__ unsigned short tile[32][33];
  int b = blockIdx.z;
  int s0 = blockIdx.x * 32, d0 = blockIdx.y * 32;
  int tx = threadIdx.x & 31, ty = threadIdx.x >> 5;
  for (int yy = ty; yy < 32; yy += 8)
    tile[yy][tx] = qkv[(size_t)(b * S + s0 + yy) * 2304 + 2176 + d0 + tx];
  __syncthreads();
  for (int yy = ty; yy < 32; yy += 8)
    vt[((size_t)b * 128 + d0 + yy) * S + s0 + tx] = tile[tx][yy];
}

// ---------------- causal flash attention (r15 verified: balanced split + reuse) ----------------
__global__ __launch_bounds__(256, 2)
void k_attn(const unsigned short* __restrict__ qr,
            const unsigned short* __restrict__ kr,
            const unsigned short* __restrict__ vt,
            unsigned short* __restrict__ attn_out,
            unsigned short* __restrict__ pscr,
            float* __restrict__ lscr,
            int S, int H) {
  const int flat = blockIdx.x + 16 * blockIdx.y + 256 * blockIdx.z;
  const int half = flat >> 8;
  const int p    = flat & 7;
  const int h    = (flat >> 3) & 15;
  const int b    = (flat >> 7) & 1;
  const int qtA = 8 + p, qtB = 7 - p;
  const int qb0A = qtA * 128, qb0B = qtB * 128;
  const int nA = 2 * qtA + 2;
  const int pg = (b * H + h) * 8 + p;

  const int tid = threadIdx.x, wid = tid >> 6, lane = tid & 63;
  const int lr = lane & 15, lk = lane >> 4;

  __shared__ unsigned short Kt[2][64 * 128];
  __shared__ unsigned short Vt[2][128 * 64];

  const char* kbyte = (const char*)(kr + (size_t)b * S * 128);
  const char* vbyte = (const char*)(vt + (size_t)b * 128 * S);
  const size_t vrow_bytes = (size_t)S * 2;

  bf16x8 aq[2][4];
  auto loadQ = [&](int qb0) {
    #pragma unroll
    for (int g = 0; g < 2; ++g) {
      const unsigned short* qptr = qr + ((size_t)(b * H + h) * S + (qb0 + wid * 32 + g * 16 + lr)) * 128;
      #pragma unroll
      for (int kk = 0; kk < 4; ++kk) aq[g][kk] = *(const bf16x8*)(qptr + kk * 32 + lk * 8);
    }
  };

  f32x4 acc[2][8];
  float ls[2];
  auto resetAcc = [&]() {
    #pragma unroll
    for (int g = 0; g < 2; ++g) {
      ls[g] = 0.f;
      #pragma unroll
      for (int t = 0; t < 8; ++t) acc[g][t] = (f32x4){0.f, 0.f, 0.f, 0.f};
    }
  };

  const int vsw = ((lr & 3) | ((lr >> 1) & 4)) << 4;
  int krow_[4], ksw_[4];
  #pragma unroll
  for (int m = 0; m < 4; ++m) {
    int row = ((m >> 1) << 5) + ((m & 1) << 2) + ((lr >> 2) << 3) + (lr & 3);
    krow_[m] = row;
    ksw_[m] = ((row & 3) | ((row >> 1) & 4)) << 4;
  }

  auto stage = [&](int buf, int kb) {
    const char* kg = kbyte + (size_t)kb * 256;
    #pragma unroll
    for (int r = 0; r < 4; ++r) {
      int row = (tid >> 4) + r * 16;
      int sw = ((row & 3) | ((row >> 1) & 4)) << 4;
      const char* src = kg + row * 256 + (((tid & 15) << 4) ^ sw);
      gload_lds16(src, (void*)((char*)&Kt[buf][0] + r * 4096 + wid * 1024));
    }
    const char* vg = vbyte + (size_t)kb * 2;
    #pragma unroll
    for (int r = 0; r < 4; ++r) {
      int d = (tid >> 3) + r * 32;
      int sw = ((d & 3) | ((d >> 1) & 4)) << 4;
      const char* src = vg + (size_t)d * vrow_bytes + (((tid & 7) << 4) ^ sw);
      gload_lds16(src, (void*)((char*)&Vt[buf][0] + r * 4096 + wid * 1024));
    }
  };

  auto itemKb = [&](int j, int& which) -> int {
    int idx = half * 17 + j;
    if (idx < nA) { which = 0; return idx * 64; }
    which = 1; return (idx - nA) * 64;
  };

  auto flushA = [&]() {
    #pragma unroll
    for (int g = 0; g < 2; ++g) {
      float v = ls[g];
      v += __shfl_xor(v, 16);
      v += __shfl_xor(v, 32);
      if (lk == 0) lscr[((size_t)pg * 2 + half) * 128 + wid * 32 + g * 16 + lr] = v;
      #pragma unroll
      for (int t = 0; t < 8; ++t)
        #pragma unroll
        for (int r = 0; r < 4; ++r) {
          int row = wid * 32 + g * 16 + lk * 4 + r;
          pscr[((size_t)pg * 2 + half) * 16384 + row * 128 + t * 16 + lr] = f2b(acc[g][t][r]);
        }
    }
  };

  auto computeTile = [&](int cur, int kb, int qb0cur) {
    const int qw = qb0cur + wid * 32;
    if (kb > qw + 31) return;
    const unsigned short* Kc = &Kt[cur][0];
    const unsigned short* Vc = &Vt[cur][0];
    f32x4 s4[2][4];
    #pragma unroll
    for (int g = 0; g < 2; ++g)
      #pragma unroll
      for (int m = 0; m < 4; ++m) s4[g][m] = (f32x4){0.f, 0.f, 0.f, 0.f};
    __builtin_amdgcn_s_setprio(1);
    #pragma unroll
    for (int kk = 0; kk < 4; ++kk) {
      bf16x8 kfk[4];
      #pragma unroll
      for (int m = 0; m < 4; ++m)
        kfk[m] = *(const bf16x8*)((const char*)Kc + krow_[m] * 256 + ((kk * 64 + lk * 16) ^ ksw_[m]));
      #pragma unroll
      for (int m = 0; m < 4; ++m) {
        s4[0][m] = __builtin_amdgcn_mfma_f32_16x16x32_bf16(kfk[m], aq[0][kk], s4[0][m], 0, 0, 0);
        s4[1][m] = __builtin_amdgcn_mfma_f32_16x16x32_bf16(kfk[m], aq[1][kk], s4[1][m], 0, 0, 0);
      }
    }
    __builtin_amdgcn_s_setprio(0);
    bf16x8 pa[2][2];
    #pragma unroll
    for (int g = 0; g < 2; ++g) {
      const int rowq = qw + g * 16 + lr;
      const bool domask = (kb + 64) > (qw + g * 16);
      uint2 pk[4];
      #pragma unroll
      for (int m = 0; m < 4; ++m) {
        const int kb_m = kb + ((m >> 1) << 5) + ((m & 1) << 2) + lk * 8;
        float pv[4];
        #pragma unroll
        for (int r = 0; r < 4; ++r) {
          float v = __expf(s4[g][m][r]);
          if (domask && (kb_m + r) > rowq) v = 0.f;
          pv[r] = v;
          ls[g] += v;
        }
        pk[m].x = pkcvt(pv[0], pv[1]);
        pk[m].y = pkcvt(pv[2], pv[3]);
      }
      uint4 ua, ub;
      ua.x = pk[0].x; ua.y = pk[0].y; ua.z = pk[1].x; ua.w = pk[1].y;
      ub.x = pk[2].x; ub.y = pk[2].y; ub.z = pk[3].x; ub.w = pk[3].y;
      pa[g][0] = __builtin_bit_cast(bf16x8, ua);
      pa[g][1] = __builtin_bit_cast(bf16x8, ub);
    }
    __builtin_amdgcn_s_setprio(1);
    #pragma unroll
    for (int t = 0; t < 8; ++t) {
      const char* vl = (const char*)(Vc + (t * 16 + lr) * 64);
      bf16x8 bv0 = *(const bf16x8*)(vl + ((lk * 16) ^ vsw));
      bf16x8 bv1 = *(const bf16x8*)(vl + ((64 + lk * 16) ^ vsw));
      acc[0][t] = __builtin_amdgcn_mfma_f32_16x16x32_bf16(pa[0][0], bv0, acc[0][t], 0, 0, 0);
      acc[1][t] = __builtin_amdgcn_mfma_f32_16x16x32_bf16(pa[1][0], bv0, acc[1][t], 0, 0, 0);
      acc[0][t] = __builtin_amdgcn_mfma_f32_16x16x32_bf16(pa[0][1], bv1, acc[0][t], 0, 0, 0);
      acc[1][t] = __builtin_amdgcn_mfma_f32_16x16x32_bf16(pa[1][1], bv1, acc[1][t], 0, 0, 0);
    }
    __builtin_amdgcn_s_setprio(0);
  };

  loadQ(qb0A);
  resetAcc();
  int curTile = 0, qb0cur = qb0A;

  {
    int wh0;
    stage(0, itemKb(0, wh0));
  }
  int cur = 0;
  #pragma unroll 1
  for (int j = 0; j < 17; ++j) {
    if (j + 1 < 17) {
      int whn;
      stage(cur ^ 1, itemKb(j + 1, whn));
      asm volatile("s_waitcnt vmcnt(8)" ::: "memory");
    } else {
      asm volatile("s_waitcnt vmcnt(0)" ::: "memory");
    }
    __builtin_amdgcn_sched_barrier(0);
    __builtin_amdgcn_s_barrier();
    int wh;
    const int kb = itemKb(j, wh);
    if (wh != curTile) {
      flushA();
      resetAcc();
      loadQ(qb0B);
      curTile = 1;
      qb0cur = qb0B;
    }
    computeTile(cur, kb, qb0cur);
    __builtin_amdgcn_s_barrier();
    cur ^= 1;
  }

  if (half == 0) {
    flushA();
  } else {
    #pragma unroll
    for (int g = 0; g < 2; ++g) {
      float v = ls[g];
      v += __shfl_xor(v, 16);
      v += __shfl_xor(v, 32);
      float rl[4];
      #pragma unroll
      for (int r = 0; r < 4; ++r) rl[r] = 1.0f / __shfl(v, lk * 4 + r);
      #pragma unroll
      for (int t = 0; t < 8; ++t) {
        #pragma unroll
        for (int r = 0; r < 4; ++r) {
          int srow = qb0B + wid * 32 + g * 16 + lk * 4 + r;
          float o = acc[g][t][r] * rl[r];
          attn_out[((size_t)(b * S) + srow) * 2048 + h * 128 + t * 16 + lr] = f2b(o);
        }
      }
    }
  }
}

// ---------------- combine A partials ----------------
__global__ void k_combine(const unsigned short* __restrict__ pscr,
                          const float* __restrict__ lscr,
                          unsigned short* __restrict__ attn_out, int S, int H) {
  const int p = blockIdx.x, h = blockIdx.y, b = blockIdx.z;
  const int pg = (b * H + h) * 8 + p;
  const int qb0A = (8 + p) * 128;
  const int tid = threadIdx.x;
  const unsigned short* p0 = pscr + (size_t)pg * 2 * 16384;
  const unsigned short* p1 = p0 + 16384;
  const float* l0 = lscr + (size_t)pg * 2 * 128;
  const float* l1 = l0 + 128;
  #pragma unroll
  for (int it = 0; it < 8; ++it) {
    int row = it * 16 + (tid >> 4);
    int col = (tid & 15) * 8;
    float rl = 1.0f / (l0[row] + l1[row]);
    ushort4 a = *(const ushort4*)(p0 + row * 128 + col);
    ushort4 c = *(const ushort4*)(p1 + row * 128 + col);
    ushort4 a2 = *(const ushort4*)(p0 + row * 128 + col + 4);
    ushort4 c2 = *(const ushort4*)(p1 + row * 128 + col + 4);
    ushort4 o1, o2;
    o1.x = f2b((b2f(a.x) + b2f(c.x)) * rl);
    o1.y = f2b((b2f(a.y) + b2f(c.y)) * rl);
    o1.z = f2b((b2f(a.z) + b2f(c.z)) * rl);
    o1.w = f2b((b2f(a.w) + b2f(c.w)) * rl);
    o2.x = f2b((b2f(a2.x) + b2f(c2.x)) * rl);
    o2.y = f2b((b2f(a2.y) + b2f(c2.y)) * rl);
    o2.z = f2b((b2f(a2.z) + b2f(c2.z)) * rl);
    o2.w = f2b((b2f(a2.w) + b2f(c2.w)) * rl);
    unsigned short* dst = attn_out + ((size_t)(b * S) + qb0A + row) * 2048 + h * 128 + col;
    *(ushort4*)dst = o1;
    *(ushort4*)(dst + 4) = o2;
  }
}

// ---------------- launch ----------------
extern "C" void kernel_launch(void* const* d_in, const int* in_sizes, int n_in,
                              void* d_out, int out_size, void* d_ws, size_t ws_size,
                              hipStream_t stream) {
  const float* x  = (const float*)d_in[0];
  const float* Wq = (const float*)d_in[1];
  const float* bq = (const float*)d_in[2];
  const float* Wk = (const float*)d_in[3];
  const float* bk = (const float*)d_in[4];
  const float* Wv = (const float*)d_in[5];
  const float* bv = (const float*)d_in[6];
  const float* Wo = (const float*)d_in[7];
  const float* bo = (const float*)d_in[8];

  const int B = 2, S = 2048, E = 2048, H = 16, D = 128;
  const int M = B * S;             // 4096
  const int Nqkv = H * D + 2 * D;  // 2304

  char* w = (char*)d_ws;
  unsigned short* xb    = (unsigned short*)w;
  unsigned short* WqkvT = (unsigned short*)(w + 16777216);
  unsigned short* qkv   = (unsigned short*)(w + 16777216 + 9437184);
  unsigned short* qr    = (unsigned short*)(w + 16777216 + 9437184 + 18874368);
  unsigned short* kr    = qr + (size_t)B * H * S * D;
  unsigned short* vtb   = kr + (size_t)B * S * D;
  float*          cbias = (float*)(vtb + (size_t)B * S * D);
  unsigned short* WoT   = (unsigned short*)(cbias + 4096);
  unsigned short* attn_out = xb;
  unsigned short* pscr  = qkv;
  float*          lscr  = (float*)WqkvT;

  k_prep<<<dim3(Nqkv / 32, E / 32, 3), 256, 0, stream>>>(Wq, Wk, Wv, Wo, x, xb, WqkvT, WoT, M * E / 4);
  k_gemm96<1><<<dim3(Nqkv / 96, M / 128), 256, 0, stream>>>(xb, WqkvT, bq, bk, bv, qkv, M, Nqkv, E);
  k_rope<<<dim3(B * S * (H + 1) / 4), 256, 0, stream>>>(qkv, qr, kr, S, H);
  k_vtrans<<<dim3(S / 32, D / 32, B), 256, 0, stream>>>(qkv, vtb, S);
  k_attn<<<dim3(16, 16, 2), 256, 0, stream>>>(qr, kr, vtb, attn_out, pscr, lscr, S, H);
  k_combine<<<dim3(8, H, B), 256, 0, stream>>>(pscr, lscr, attn_out, S, H);
  k_gemm2<<<dim3(E / 64, M / 128), 256, 0, stream>>>(attn_out, WoT, bo, (float*)d_out, M, E, H * D);
}

// Round 20
// 193.639 us; speedup vs baseline: 1.0441x; 1.0441x over previous
//
#include <hip/hip_runtime.h>
#include <stdint.h>

typedef __bf16 bf16x8 __attribute__((ext_vector_type(8)));
typedef __bf16 bf16x2 __attribute__((ext_vector_type(2)));
typedef float  f32x4  __attribute__((ext_vector_type(4)));

__device__ inline unsigned short f2b(float f) {
  unsigned int u = __builtin_bit_cast(unsigned int, f);
  u += 0x7FFFu + ((u >> 16) & 1u);
  return (unsigned short)(u >> 16);
}
__device__ inline float b2f(unsigned short h) {
  unsigned int u = ((unsigned int)h) << 16;
  return __builtin_bit_cast(float, u);
}
__device__ inline unsigned int pkcvt(float a, float b) {
  bf16x2 t;
  t[0] = (__bf16)a;
  t[1] = (__bf16)b;
  return __builtin_bit_cast(unsigned int, t);
}
__device__ inline void gload_lds16(const void* g, void* l) {
  __builtin_amdgcn_global_load_lds(
      (const __attribute__((address_space(1))) unsigned int*)g,
      (__attribute__((address_space(3))) unsigned int*)l, 16, 0, 0);
}

// ---------------- prep: z=0 Wq|Wk|Wv transpose, z=1 Wo transpose, z=2 x cvt ----------------
__global__ void k_prep(const float* __restrict__ Wq, const float* __restrict__ Wk,
                       const float* __restrict__ Wv, const float* __restrict__ Wo,
                       const float* __restrict__ x, unsigned short* __restrict__ xb,
                       unsigned short* __restrict__ dstQKV, unsigned short* __restrict__ dstO,
                       int n4) {
  if (blockIdx.z == 2) {
    int nblk = gridDim.x * gridDim.y;
    int bid = blockIdx.y * gridDim.x + blockIdx.x;
    for (int i = bid * 256 + threadIdx.x; i < n4; i += nblk * 256) {
      float4 v = ((const float4*)x)[i];
      ushort4 o;
      o.x = f2b(v.x); o.y = f2b(v.y); o.z = f2b(v.z); o.w = f2b(v.w);
      ((ushort4*)xb)[i] = o;
    }
    return;
  }
  __shared__ float tile[32][33];
  int n0 = blockIdx.x * 32;
  int k0 = blockIdx.y * 32;
  const float* src; int ldn, noff, K;
  unsigned short* dst;
  if (blockIdx.z == 0) {
    K = 2048; dst = dstQKV;
    if (n0 < 2048)       { src = Wq; ldn = 2048; noff = n0; }
    else if (n0 < 2176)  { src = Wk; ldn = 128;  noff = n0 - 2048; }
    else                 { src = Wv; ldn = 128;  noff = n0 - 2176; }
  } else {
    if (n0 >= 2048) return;
    K = 2048; dst = dstO;
    src = Wo; ldn = 2048; noff = n0;
  }
  int tx = threadIdx.x & 31, ty = threadIdx.x >> 5;
  for (int yy = ty; yy < 32; yy += 8)
    tile[yy][tx] = src[(size_t)(k0 + yy) * ldn + noff + tx];
  __syncthreads();
  for (int yy = ty; yy < 32; yy += 8)
    dst[(size_t)(n0 + yy) * K + k0 + tx] = f2b(tile[tx][yy]);
}

// ---------------- bf16 GEMM, 128x96 tile (GEMM1: balanced 768 = 3/CU) ----------------
template<int BIAS3>
__global__ __launch_bounds__(256)
void k_gemm96(const unsigned short* __restrict__ A, const unsigned short* __restrict__ Bt,
              const float* __restrict__ b0, const float* __restrict__ b1,
              const float* __restrict__ b2, unsigned short* __restrict__ Cout,
              int M, int N, int K) {
  __shared__ unsigned short As[3][4096];   // 128x32
  __shared__ unsigned short Bs[3][3072];   // 96x32
  const int tid  = threadIdx.x;
  const int lane = tid & 63, wid = tid >> 6;
  const int lr = lane & 15, lk = lane >> 4;
  const int wr = wid >> 1,  wc = wid & 1;

  const int nwg = gridDim.x * gridDim.y;
  const int flat = blockIdx.y * gridDim.x + blockIdx.x;
  const int swz = (flat & 7) * (nwg >> 3) + (flat >> 3);
  const int mb = (swz / gridDim.x) * 128;
  const int nb = (swz % gridDim.x) * 96;

  const int srow = tid >> 2, scb = (tid & 3) * 8;
  const size_t gA = (size_t)(mb + srow) * K + scb;
  const int brow0 = wid * 32 + (lane >> 2);
  const int bcol  = (lane & 3) * 8;
  const size_t gB = (size_t)(nb + brow0) * K + bcol;
  const int bdst0 = (wid * 128 + lane) * 16;

  f32x4 acc[4][3];
  #pragma unroll
  for (int i = 0; i < 4; ++i)
    #pragma unroll
    for (int j = 0; j < 3; ++j) acc[i][j] = (f32x4){0.f, 0.f, 0.f, 0.f};

  auto stage = [&](int buf, int kt) {
    const size_t ko = (size_t)kt * 32;
    gload_lds16(A + gA + ko,                  &As[buf][(tid) * 8]);
    gload_lds16(A + gA + 64 * (size_t)K + ko, &As[buf][2048 + tid * 8]);
    if (wid < 3) {
      gload_lds16(Bt + gB + ko,                  (char*)&Bs[buf][0] + bdst0);
      gload_lds16(Bt + gB + 16 * (size_t)K + ko, (char*)&Bs[buf][0] + bdst0 + 1024);
    }
  };

  const int ktn = K >> 5;
  stage(0, 0);
  stage(1, 1);

  int cur = 0;
  #pragma unroll 1
  for (int kt = 0; kt < ktn; ++kt) {
    if (kt + 2 < ktn) {
      int nbuf = cur + 2; if (nbuf >= 3) nbuf -= 3;
      stage(nbuf, kt + 2);
      if (wid < 3) asm volatile("s_waitcnt vmcnt(8)" ::: "memory");
      else         asm volatile("s_waitcnt vmcnt(4)" ::: "memory");
    } else if (kt + 1 < ktn) {
      if (wid < 3) asm volatile("s_waitcnt vmcnt(4)" ::: "memory");
      else         asm volatile("s_waitcnt vmcnt(2)" ::: "memory");
    } else {
      asm volatile("s_waitcnt vmcnt(0)" ::: "memory");
    }
    __builtin_amdgcn_sched_barrier(0);
    __builtin_amdgcn_s_barrier();
    bf16x8 af[4], bfv[3];
    #pragma unroll
    for (int m = 0; m < 4; ++m)
      af[m]  = *(const bf16x8*)&As[cur][(wr * 64 + m * 16 + lr) * 32 + lk * 8];
    #pragma unroll
    for (int n = 0; n < 3; ++n)
      bfv[n] = *(const bf16x8*)&Bs[cur][(wc * 48 + n * 16 + lr) * 32 + lk * 8];
    #pragma unroll
    for (int m = 0; m < 4; ++m)
      #pragma unroll
      for (int n = 0; n < 3; ++n)
        acc[m][n] = __builtin_amdgcn_mfma_f32_16x16x32_bf16(af[m], bfv[n], acc[m][n], 0, 0, 0);
    __builtin_amdgcn_s_barrier();
    ++cur; if (cur == 3) cur = 0;
  }

  const int r0 = mb + wr * 64, c0 = nb + wc * 48;
  #pragma unroll
  for (int m = 0; m < 4; ++m) {
    #pragma unroll
    for (int n = 0; n < 3; ++n) {
      int col = c0 + n * 16 + lr;
      float bb;
      if (BIAS3) bb = (col < 2048) ? b0[col] : (col < 2176 ? b1[col - 2048] : b2[col - 2176]);
      else       bb = b0[col];
      #pragma unroll
      for (int r = 0; r < 4; ++r) {
        int row = r0 + m * 16 + lk * 4 + r;
        Cout[(size_t)row * N + col] = f2b(acc[m][n][r] + bb);
      }
    }
  }
}

// ---------------- GEMM2: 128x128, 3-ring, counted vmcnt (r18 verified); f32 out ----------------
__global__ __launch_bounds__(256)
void k_gemm2(const unsigned short* __restrict__ A, const unsigned short* __restrict__ Bt,
             const float* __restrict__ b0, float* __restrict__ Cout,
             int M, int N, int K) {
  __shared__ unsigned short As[3][4096];
  __shared__ unsigned short Bs[3][4096];
  const int tid  = threadIdx.x;
  const int lane = tid & 63, wid = tid >> 6;
  const int lr = lane & 15, lk = lane >> 4;
  const int wr = wid >> 1,  wc = wid & 1;

  const int nwg = gridDim.x * gridDim.y;
  const int flat = blockIdx.y * gridDim.x + blockIdx.x;
  const int swz = (flat & 7) * (nwg >> 3) + (flat >> 3);
  const int mb = (swz / gridDim.x) * 128;
  const int nb = (swz % gridDim.x) * 128;

  const int srow = tid >> 2, scb = (tid & 3) * 8;
  const size_t gA = (size_t)(mb + srow) * K + scb;
  const size_t gB = (size_t)(nb + srow) * K + scb;
  const int ldso = wid * 512;

  f32x4 acc[4][4];
  #pragma unroll
  for (int i = 0; i < 4; ++i)
    #pragma unroll
    for (int j = 0; j < 4; ++j) acc[i][j] = (f32x4){0.f, 0.f, 0.f, 0.f};

  auto stage = [&](int buf, int kt) {
    const size_t ko = (size_t)kt * 32;
    gload_lds16(A  + gA + ko,                  &As[buf][ldso]);
    gload_lds16(A  + gA + 64 * (size_t)K + ko, &As[buf][2048 + ldso]);
    gload_lds16(Bt + gB + ko,                  &Bs[buf][ldso]);
    gload_lds16(Bt + gB + 64 * (size_t)K + ko, &Bs[buf][2048 + ldso]);
  };

  const int ktn = K >> 5;
  stage(0, 0);
  stage(1, 1);

  int cur = 0;
  #pragma unroll 1
  for (int kt = 0; kt < ktn; ++kt) {
    if (kt + 2 < ktn) {
      int nbuf = cur + 2; if (nbuf >= 3) nbuf -= 3;
      stage(nbuf, kt + 2);
      asm volatile("s_waitcnt vmcnt(8)" ::: "memory");
    } else if (kt + 1 < ktn) {
      asm volatile("s_waitcnt vmcnt(4)" ::: "memory");
    } else {
      asm volatile("s_waitcnt vmcnt(0)" ::: "memory");
    }
    __builtin_amdgcn_sched_barrier(0);
    __builtin_amdgcn_s_barrier();
    bf16x8 af[4], bfv[4];
    #pragma unroll
    for (int m = 0; m < 4; ++m)
      af[m]  = *(const bf16x8*)&As[cur][(wr * 64 + m * 16 + lr) * 32 + lk * 8];
    #pragma unroll
    for (int n = 0; n < 4; ++n)
      bfv[n] = *(const bf16x8*)&Bs[cur][(wc * 64 + n * 16 + lr) * 32 + lk * 8];
    #pragma unroll
    for (int m = 0; m < 4; ++m)
      #pragma unroll
      for (int n = 0; n < 4; ++n)
        acc[m][n] = __builtin_amdgcn_mfma_f32_16x16x32_bf16(af[m], bfv[n], acc[m][n], 0, 0, 0);
    __builtin_amdgcn_s_barrier();
    ++cur; if (cur == 3) cur = 0;
  }

  const int r0 = mb + wr * 64, c0 = nb + wc * 64;
  #pragma unroll
  for (int m = 0; m < 4; ++m) {
    #pragma unroll
    for (int n = 0; n < 4; ++n) {
      int col = c0 + n * 16 + lr;
      float bb = b0[col];
      #pragma unroll
      for (int r = 0; r < 4; ++r) {
        int row = r0 + m * 16 + lk * 4 + r;
        Cout[(size_t)row * N + col] = acc[m][n][r] + bb;
      }
    }
  }
}

// ---------------- RoPE (q heads + k); q pre-scaled by 1/sqrt(D) ----------------
__global__ void k_rope(const unsigned short* __restrict__ qkv,
                       unsigned short* __restrict__ qr,
                       unsigned short* __restrict__ kr,
                       int S, int H) {
  int R = blockIdx.x * 4 + (threadIdx.x >> 6);
  int lane = threadIdx.x & 63;
  int per_b = S * (H + 1);
  int b = R / per_b;
  int rem = R - b * per_b;
  int s = rem / (H + 1);
  int j = rem - s * (H + 1);
  const unsigned short* src = qkv + (size_t)(b * S + s) * 2304 + (j < H ? j * 128 : 2048);
  float x1 = b2f(src[lane]);
  float x2 = b2f(src[lane + 64]);
  float invf = expf(-(float)lane * (9.210340371976184f / 64.0f));
  float ang = (float)s * invf;
  float c = cosf(ang), sn = sinf(ang);
  float o1 = x1 * c - x2 * sn;
  float o2 = x1 * sn + x2 * c;
  unsigned short* dst;
  if (j < H) {
    const float scale = 0.08838834764831845f;
    o1 *= scale; o2 *= scale;
    dst = qr + ((size_t)(b * H + j) * S + s) * 128;
  } else {
    dst = kr + ((size_t)(b * S) + s) * 128;
  }
  dst[lane]      = f2b(o1);
  dst[lane + 64] = f2b(o2);
}

// ---------------- V transpose ----------------
__global__ void k_vtrans(const unsigned short* __restrict__ qkv,
                         unsigned short* __restrict__ vt, int S) {
  __shared__ unsigned short tile[32][33];
  int b = blockIdx.z;
  int s0 = blockIdx.x * 32, d0 = blockIdx.y * 32;
  int tx = threadIdx.x & 31, ty = threadIdx.x >> 5;
  for (int yy = ty; yy < 32; yy += 8)
    tile[yy][tx] = qkv[(size_t)(b * S + s0 + yy) * 2304 + 2176 + d0 + tx];
  __syncthreads();
  for (int yy = ty; yy < 32; yy += 8)
    vt[((size_t)b * 128 + d0 + yy) * S + s0 + tx] = tile[tx][yy];
}

// ---------------- causal flash attention (r15 verified: balanced split + reuse) ----------------
__global__ __launch_bounds__(256, 2)
void k_attn(const unsigned short* __restrict__ qr,
            const unsigned short* __restrict__ kr,
            const unsigned short* __restrict__ vt,
            unsigned short* __restrict__ attn_out,
            unsigned short* __restrict__ pscr,
            float* __restrict__ lscr,
            int S, int H) {
  const int flat = blockIdx.x + 16 * blockIdx.y + 256 * blockIdx.z;
  const int half = flat >> 8;
  const int p    = flat & 7;
  const int h    = (flat >> 3) & 15;
  const int b    = (flat >> 7) & 1;
  const int qtA = 8 + p, qtB = 7 - p;
  const int qb0A = qtA * 128, qb0B = qtB * 128;
  const int nA = 2 * qtA + 2;
  const int pg = (b * H + h) * 8 + p;

  const int tid = threadIdx.x, wid = tid >> 6, lane = tid & 63;
  const int lr = lane & 15, lk = lane >> 4;

  __shared__ unsigned short Kt[2][64 * 128];
  __shared__ unsigned short Vt[2][128 * 64];

  const char* kbyte = (const char*)(kr + (size_t)b * S * 128);
  const char* vbyte = (const char*)(vt + (size_t)b * 128 * S);
  const size_t vrow_bytes = (size_t)S * 2;

  bf16x8 aq[2][4];
  auto loadQ = [&](int qb0) {
    #pragma unroll
    for (int g = 0; g < 2; ++g) {
      const unsigned short* qptr = qr + ((size_t)(b * H + h) * S + (qb0 + wid * 32 + g * 16 + lr)) * 128;
      #pragma unroll
      for (int kk = 0; kk < 4; ++kk) aq[g][kk] = *(const bf16x8*)(qptr + kk * 32 + lk * 8);
    }
  };

  f32x4 acc[2][8];
  float ls[2];
  auto resetAcc = [&]() {
    #pragma unroll
    for (int g = 0; g < 2; ++g) {
      ls[g] = 0.f;
      #pragma unroll
      for (int t = 0; t < 8; ++t) acc[g][t] = (f32x4){0.f, 0.f, 0.f, 0.f};
    }
  };

  const int vsw = ((lr & 3) | ((lr >> 1) & 4)) << 4;
  int krow_[4], ksw_[4];
  #pragma unroll
  for (int m = 0; m < 4; ++m) {
    int row = ((m >> 1) << 5) + ((m & 1) << 2) + ((lr >> 2) << 3) + (lr & 3);
    krow_[m] = row;
    ksw_[m] = ((row & 3) | ((row >> 1) & 4)) << 4;
  }

  auto stage = [&](int buf, int kb) {
    const char* kg = kbyte + (size_t)kb * 256;
    #pragma unroll
    for (int r = 0; r < 4; ++r) {
      int row = (tid >> 4) + r * 16;
      int sw = ((row & 3) | ((row >> 1) & 4)) << 4;
      const char* src = kg + row * 256 + (((tid & 15) << 4) ^ sw);
      gload_lds16(src, (void*)((char*)&Kt[buf][0] + r * 4096 + wid * 1024));
    }
    const char* vg = vbyte + (size_t)kb * 2;
    #pragma unroll
    for (int r = 0; r < 4; ++r) {
      int d = (tid >> 3) + r * 32;
      int sw = ((d & 3) | ((d >> 1) & 4)) << 4;
      const char* src = vg + (size_t)d * vrow_bytes + (((tid & 7) << 4) ^ sw);
      gload_lds16(src, (void*)((char*)&Vt[buf][0] + r * 4096 + wid * 1024));
    }
  };

  auto itemKb = [&](int j, int& which) -> int {
    int idx = half * 17 + j;
    if (idx < nA) { which = 0; return idx * 64; }
    which = 1; return (idx - nA) * 64;
  };

  auto flushA = [&]() {
    #pragma unroll
    for (int g = 0; g < 2; ++g) {
      float v = ls[g];
      v += __shfl_xor(v, 16);
      v += __shfl_xor(v, 32);
      if (lk == 0) lscr[((size_t)pg * 2 + half) * 128 + wid * 32 + g * 16 + lr] = v;
      #pragma unroll
      for (int t = 0; t < 8; ++t)
        #pragma unroll
        for (int r = 0; r < 4; ++r) {
          int row = wid * 32 + g * 16 + lk * 4 + r;
          pscr[((size_t)pg * 2 + half) * 16384 + row * 128 + t * 16 + lr] = f2b(acc[g][t][r]);
        }
    }
  };

  auto computeTile = [&](int cur, int kb, int qb0cur) {
    const int qw = qb0cur + wid * 32;
    if (kb > qw + 31) return;
    const unsigned short* Kc = &Kt[cur][0];
    const unsigned short* Vc = &Vt[cur][0];
    f32x4 s4[2][4];
    #pragma unroll
    for (int g = 0; g < 2; ++g)
      #pragma unroll
      for (int m = 0; m < 4; ++m) s4[g][m] = (f32x4){0.f, 0.f, 0.f, 0.f};
    __builtin_amdgcn_s_setprio(1);
    #pragma unroll
    for (int kk = 0; kk < 4; ++kk) {
      bf16x8 kfk[4];
      #pragma unroll
      for (int m = 0; m < 4; ++m)
        kfk[m] = *(const bf16x8*)((const char*)Kc + krow_[m] * 256 + ((kk * 64 + lk * 16) ^ ksw_[m]));
      #pragma unroll
      for (int m = 0; m < 4; ++m) {
        s4[0][m] = __builtin_amdgcn_mfma_f32_16x16x32_bf16(kfk[m], aq[0][kk], s4[0][m], 0, 0, 0);
        s4[1][m] = __builtin_amdgcn_mfma_f32_16x16x32_bf16(kfk[m], aq[1][kk], s4[1][m], 0, 0, 0);
      }
    }
    __builtin_amdgcn_s_setprio(0);
    bf16x8 pa[2][2];
    #pragma unroll
    for (int g = 0; g < 2; ++g) {
      const int rowq = qw + g * 16 + lr;
      const bool domask = (kb + 64) > (qw + g * 16);
      uint2 pk[4];
      #pragma unroll
      for (int m = 0; m < 4; ++m) {
        const int kb_m = kb + ((m >> 1) << 5) + ((m & 1) << 2) + lk * 8;
        float pv[4];
        #pragma unroll
        for (int r = 0; r < 4; ++r) {
          float v = __expf(s4[g][m][r]);
          if (domask && (kb_m + r) > rowq) v = 0.f;
          pv[r] = v;
          ls[g] += v;
        }
        pk[m].x = pkcvt(pv[0], pv[1]);
        pk[m].y = pkcvt(pv[2], pv[3]);
      }
      uint4 ua, ub;
      ua.x = pk[0].x; ua.y = pk[0].y; ua.z = pk[1].x; ua.w = pk[1].y;
      ub.x = pk[2].x; ub.y = pk[2].y; ub.z = pk[3].x; ub.w = pk[3].y;
      pa[g][0] = __builtin_bit_cast(bf16x8, ua);
      pa[g][1] = __builtin_bit_cast(bf16x8, ub);
    }
    __builtin_amdgcn_s_setprio(1);
    #pragma unroll
    for (int t = 0; t < 8; ++t) {
      const char* vl = (const char*)(Vc + (t * 16 + lr) * 64);
      bf16x8 bv0 = *(const bf16x8*)(vl + ((lk * 16) ^ vsw));
      bf16x8 bv1 = *(const bf16x8*)(vl + ((64 + lk * 16) ^ vsw));
      acc[0][t] = __builtin_amdgcn_mfma_f32_16x16x32_bf16(pa[0][0], bv0, acc[0][t], 0, 0, 0);
      acc[1][t] = __builtin_amdgcn_mfma_f32_16x16x32_bf16(pa[1][0], bv0, acc[1][t], 0, 0, 0);
      acc[0][t] = __builtin_amdgcn_mfma_f32_16x16x32_bf16(pa[0][1], bv1, acc[0][t], 0, 0, 0);
      acc[1][t] = __builtin_amdgcn_mfma_f32_16x16x32_bf16(pa[1][1], bv1, acc[1][t], 0, 0, 0);
    }
    __builtin_amdgcn_s_setprio(0);
  };

  loadQ(qb0A);
  resetAcc();
  int curTile = 0, qb0cur = qb0A;

  {
    int wh0;
    stage(0, itemKb(0, wh0));
  }
  int cur = 0;
  #pragma unroll 1
  for (int j = 0; j < 17; ++j) {
    if (j + 1 < 17) {
      int whn;
      stage(cur ^ 1, itemKb(j + 1, whn));
      asm volatile("s_waitcnt vmcnt(8)" ::: "memory");
    } else {
      asm volatile("s_waitcnt vmcnt(0)" ::: "memory");
    }
    __builtin_amdgcn_sched_barrier(0);
    __builtin_amdgcn_s_barrier();
    int wh;
    const int kb = itemKb(j, wh);
    if (wh != curTile) {
      flushA();
      resetAcc();
      loadQ(qb0B);
      curTile = 1;
      qb0cur = qb0B;
    }
    computeTile(cur, kb, qb0cur);
    __builtin_amdgcn_s_barrier();
    cur ^= 1;
  }

  if (half == 0) {
    flushA();
  } else {
    #pragma unroll
    for (int g = 0; g < 2; ++g) {
      float v = ls[g];
      v += __shfl_xor(v, 16);
      v += __shfl_xor(v, 32);
      float rl[4];
      #pragma unroll
      for (int r = 0; r < 4; ++r) rl[r] = 1.0f / __shfl(v, lk * 4 + r);
      #pragma unroll
      for (int t = 0; t < 8; ++t) {
        #pragma unroll
        for (int r = 0; r < 4; ++r) {
          int srow = qb0B + wid * 32 + g * 16 + lk * 4 + r;
          float o = acc[g][t][r] * rl[r];
          attn_out[((size_t)(b * S) + srow) * 2048 + h * 128 + t * 16 + lr] = f2b(o);
        }
      }
    }
  }
}

// ---------------- combine A partials ----------------
__global__ void k_combine(const unsigned short* __restrict__ pscr,
                          const float* __restrict__ lscr,
                          unsigned short* __restrict__ attn_out, int S, int H) {
  const int p = blockIdx.x, h = blockIdx.y, b = blockIdx.z;
  const int pg = (b * H + h) * 8 + p;
  const int qb0A = (8 + p) * 128;
  const int tid = threadIdx.x;
  const unsigned short* p0 = pscr + (size_t)pg * 2 * 16384;
  const unsigned short* p1 = p0 + 16384;
  const float* l0 = lscr + (size_t)pg * 2 * 128;
  const float* l1 = l0 + 128;
  #pragma unroll
  for (int it = 0; it < 8; ++it) {
    int row = it * 16 + (tid >> 4);
    int col = (tid & 15) * 8;
    float rl = 1.0f / (l0[row] + l1[row]);
    ushort4 a = *(const ushort4*)(p0 + row * 128 + col);
    ushort4 c = *(const ushort4*)(p1 + row * 128 + col);
    ushort4 a2 = *(const ushort4*)(p0 + row * 128 + col + 4);
    ushort4 c2 = *(const ushort4*)(p1 + row * 128 + col + 4);
    ushort4 o1, o2;
    o1.x = f2b((b2f(a.x) + b2f(c.x)) * rl);
    o1.y = f2b((b2f(a.y) + b2f(c.y)) * rl);
    o1.z = f2b((b2f(a.z) + b2f(c.z)) * rl);
    o1.w = f2b((b2f(a.w) + b2f(c.w)) * rl);
    o2.x = f2b((b2f(a2.x) + b2f(c2.x)) * rl);
    o2.y = f2b((b2f(a2.y) + b2f(c2.y)) * rl);
    o2.z = f2b((b2f(a2.z) + b2f(c2.z)) * rl);
    o2.w = f2b((b2f(a2.w) + b2f(c2.w)) * rl);
    unsigned short* dst = attn_out + ((size_t)(b * S) + qb0A + row) * 2048 + h * 128 + col;
    *(ushort4*)dst = o1;
    *(ushort4*)(dst + 4) = o2;
  }
}

// ---------------- launch ----------------
extern "C" void kernel_launch(void* const* d_in, const int* in_sizes, int n_in,
                              void* d_out, int out_size, void* d_ws, size_t ws_size,
                              hipStream_t stream) {
  const float* x  = (const float*)d_in[0];
  const float* Wq = (const float*)d_in[1];
  const float* bq = (const float*)d_in[2];
  const float* Wk = (const float*)d_in[3];
  const float* bk = (const float*)d_in[4];
  const float* Wv = (const float*)d_in[5];
  const float* bv = (const float*)d_in[6];
  const float* Wo = (const float*)d_in[7];
  const float* bo = (const float*)d_in[8];

  const int B = 2, S = 2048, E = 2048, H = 16, D = 128;
  const int M = B * S;             // 4096
  const int Nqkv = H * D + 2 * D;  // 2304

  char* w = (char*)d_ws;
  unsigned short* xb    = (unsigned short*)w;
  unsigned short* WqkvT = (unsigned short*)(w + 16777216);
  unsigned short* qkv   = (unsigned short*)(w + 16777216 + 9437184);
  unsigned short* qr    = (unsigned short*)(w + 16777216 + 9437184 + 18874368);
  unsigned short* kr    = qr + (size_t)B * H * S * D;
  unsigned short* vtb   = kr + (size_t)B * S * D;
  float*          cbias = (float*)(vtb + (size_t)B * S * D);
  unsigned short* WoT   = (unsigned short*)(cbias + 4096);
  unsigned short* attn_out = xb;
  unsigned short* pscr  = qkv;
  float*          lscr  = (float*)WqkvT;

  k_prep<<<dim3(Nqkv / 32, E / 32, 3), 256, 0, stream>>>(Wq, Wk, Wv, Wo, x, xb, WqkvT, WoT, M * E / 4);
  k_gemm96<1><<<dim3(Nqkv / 96, M / 128), 256, 0, stream>>>(xb, WqkvT, bq, bk, bv, qkv, M, Nqkv, E);
  k_rope<<<dim3(B * S * (H + 1) / 4), 256, 0, stream>>>(qkv, qr, kr, S, H);
  k_vtrans<<<dim3(S / 32, D / 32, B), 256, 0, stream>>>(qkv, vtb, S);
  k_attn<<<dim3(16, 16, 2), 256, 0, stream>>>(qr, kr, vtb, attn_out, pscr, lscr, S, H);
  k_combine<<<dim3(8, H, B), 256, 0, stream>>>(pscr, lscr, attn_out, S, H);
  k_gemm2<<<dim3(E / 128, M / 128), 256, 0, stream>>>(attn_out, WoT, bo, (float*)d_out, M, E, H * D);
}

// Round 21
// 190.481 us; speedup vs baseline: 1.0614x; 1.0166x over previous
//
#include <hip/hip_runtime.h>
#include <stdint.h>

typedef __bf16 bf16x8 __attribute__((ext_vector_type(8)));
typedef __bf16 bf16x2 __attribute__((ext_vector_type(2)));
typedef float  f32x4  __attribute__((ext_vector_type(4)));

__device__ inline unsigned short f2b(float f) {
  unsigned int u = __builtin_bit_cast(unsigned int, f);
  u += 0x7FFFu + ((u >> 16) & 1u);
  return (unsigned short)(u >> 16);
}
__device__ inline float b2f(unsigned short h) {
  unsigned int u = ((unsigned int)h) << 16;
  return __builtin_bit_cast(float, u);
}
__device__ inline unsigned int pkcvt(float a, float b) {
  bf16x2 t;
  t[0] = (__bf16)a;
  t[1] = (__bf16)b;
  return __builtin_bit_cast(unsigned int, t);
}
__device__ inline void gload_lds16(const void* g, void* l) {
  __builtin_amdgcn_global_load_lds(
      (const __attribute__((address_space(1))) unsigned int*)g,
      (__attribute__((address_space(3))) unsigned int*)l, 16, 0, 0);
}

// ---------------- prep: z=0 Wq|Wk|Wv transpose, z=1 Wo transpose, z=2 x cvt ----------------
__global__ void k_prep(const float* __restrict__ Wq, const float* __restrict__ Wk,
                       const float* __restrict__ Wv, const float* __restrict__ Wo,
                       const float* __restrict__ x, unsigned short* __restrict__ xb,
                       unsigned short* __restrict__ dstQKV, unsigned short* __restrict__ dstO,
                       int n4) {
  if (blockIdx.z == 2) {
    int nblk = gridDim.x * gridDim.y;
    int bid = blockIdx.y * gridDim.x + blockIdx.x;
    for (int i = bid * 256 + threadIdx.x; i < n4; i += nblk * 256) {
      float4 v = ((const float4*)x)[i];
      ushort4 o;
      o.x = f2b(v.x); o.y = f2b(v.y); o.z = f2b(v.z); o.w = f2b(v.w);
      ((ushort4*)xb)[i] = o;
    }
    return;
  }
  __shared__ float tile[32][33];
  int n0 = blockIdx.x * 32;
  int k0 = blockIdx.y * 32;
  const float* src; int ldn, noff, K;
  unsigned short* dst;
  if (blockIdx.z == 0) {
    K = 2048; dst = dstQKV;
    if (n0 < 2048)       { src = Wq; ldn = 2048; noff = n0; }
    else if (n0 < 2176)  { src = Wk; ldn = 128;  noff = n0 - 2048; }
    else                 { src = Wv; ldn = 128;  noff = n0 - 2176; }
  } else {
    if (n0 >= 2048) return;
    K = 2048; dst = dstO;
    src = Wo; ldn = 2048; noff = n0;
  }
  int tx = threadIdx.x & 31, ty = threadIdx.x >> 5;
  for (int yy = ty; yy < 32; yy += 8)
    tile[yy][tx] = src[(size_t)(k0 + yy) * ldn + noff + tx];
  __syncthreads();
  for (int yy = ty; yy < 32; yy += 8)
    dst[(size_t)(n0 + yy) * K + k0 + tx] = f2b(tile[tx][yy]);
}

// ---------------- bf16 GEMM, 128x96 tile (GEMM1: balanced 768 = 3/CU) ----------------
template<int BIAS3>
__global__ __launch_bounds__(256)
void k_gemm96(const unsigned short* __restrict__ A, const unsigned short* __restrict__ Bt,
              const float* __restrict__ b0, const float* __restrict__ b1,
              const float* __restrict__ b2, unsigned short* __restrict__ Cout,
              int M, int N, int K) {
  __shared__ unsigned short As[3][4096];   // 128x32
  __shared__ unsigned short Bs[3][3072];   // 96x32
  const int tid  = threadIdx.x;
  const int lane = tid & 63, wid = tid >> 6;
  const int lr = lane & 15, lk = lane >> 4;
  const int wr = wid >> 1,  wc = wid & 1;

  const int nwg = gridDim.x * gridDim.y;
  const int flat = blockIdx.y * gridDim.x + blockIdx.x;
  const int swz = (flat & 7) * (nwg >> 3) + (flat >> 3);
  const int mb = (swz / gridDim.x) * 128;
  const int nb = (swz % gridDim.x) * 96;

  const int srow = tid >> 2, scb = (tid & 3) * 8;
  const size_t gA = (size_t)(mb + srow) * K + scb;
  const int brow0 = wid * 32 + (lane >> 2);
  const int bcol  = (lane & 3) * 8;
  const size_t gB = (size_t)(nb + brow0) * K + bcol;
  const int bdst0 = (wid * 128 + lane) * 16;

  f32x4 acc[4][3];
  #pragma unroll
  for (int i = 0; i < 4; ++i)
    #pragma unroll
    for (int j = 0; j < 3; ++j) acc[i][j] = (f32x4){0.f, 0.f, 0.f, 0.f};

  auto stage = [&](int buf, int kt) {
    const size_t ko = (size_t)kt * 32;
    gload_lds16(A + gA + ko,                  &As[buf][(tid) * 8]);
    gload_lds16(A + gA + 64 * (size_t)K + ko, &As[buf][2048 + tid * 8]);
    if (wid < 3) {
      gload_lds16(Bt + gB + ko,                  (char*)&Bs[buf][0] + bdst0);
      gload_lds16(Bt + gB + 16 * (size_t)K + ko, (char*)&Bs[buf][0] + bdst0 + 1024);
    }
  };

  const int ktn = K >> 5;
  stage(0, 0);
  stage(1, 1);

  int cur = 0;
  #pragma unroll 1
  for (int kt = 0; kt < ktn; ++kt) {
    if (kt + 2 < ktn) {
      int nbuf = cur + 2; if (nbuf >= 3) nbuf -= 3;
      stage(nbuf, kt + 2);
      if (wid < 3) asm volatile("s_waitcnt vmcnt(8)" ::: "memory");
      else         asm volatile("s_waitcnt vmcnt(4)" ::: "memory");
    } else if (kt + 1 < ktn) {
      if (wid < 3) asm volatile("s_waitcnt vmcnt(4)" ::: "memory");
      else         asm volatile("s_waitcnt vmcnt(2)" ::: "memory");
    } else {
      asm volatile("s_waitcnt vmcnt(0)" ::: "memory");
    }
    __builtin_amdgcn_sched_barrier(0);
    __builtin_amdgcn_s_barrier();
    bf16x8 af[4], bfv[3];
    #pragma unroll
    for (int m = 0; m < 4; ++m)
      af[m]  = *(const bf16x8*)&As[cur][(wr * 64 + m * 16 + lr) * 32 + lk * 8];
    #pragma unroll
    for (int n = 0; n < 3; ++n)
      bfv[n] = *(const bf16x8*)&Bs[cur][(wc * 48 + n * 16 + lr) * 32 + lk * 8];
    #pragma unroll
    for (int m = 0; m < 4; ++m)
      #pragma unroll
      for (int n = 0; n < 3; ++n)
        acc[m][n] = __builtin_amdgcn_mfma_f32_16x16x32_bf16(af[m], bfv[n], acc[m][n], 0, 0, 0);
    __builtin_amdgcn_s_barrier();
    ++cur; if (cur == 3) cur = 0;
  }

  const int r0 = mb + wr * 64, c0 = nb + wc * 48;
  #pragma unroll
  for (int m = 0; m < 4; ++m) {
    #pragma unroll
    for (int n = 0; n < 3; ++n) {
      int col = c0 + n * 16 + lr;
      float bb;
      if (BIAS3) bb = (col < 2048) ? b0[col] : (col < 2176 ? b1[col - 2048] : b2[col - 2176]);
      else       bb = b0[col];
      #pragma unroll
      for (int r = 0; r < 4; ++r) {
        int row = r0 + m * 16 + lk * 4 + r;
        Cout[(size_t)row * N + col] = f2b(acc[m][n][r] + bb);
      }
    }
  }
}

// ---------------- GEMM2: 128x128, 3-ring, counted vmcnt (r18 verified); f32 out ----------------
__global__ __launch_bounds__(256)
void k_gemm2(const unsigned short* __restrict__ A, const unsigned short* __restrict__ Bt,
             const float* __restrict__ b0, float* __restrict__ Cout,
             int M, int N, int K) {
  __shared__ unsigned short As[3][4096];
  __shared__ unsigned short Bs[3][4096];
  const int tid  = threadIdx.x;
  const int lane = tid & 63, wid = tid >> 6;
  const int lr = lane & 15, lk = lane >> 4;
  const int wr = wid >> 1,  wc = wid & 1;

  const int nwg = gridDim.x * gridDim.y;
  const int flat = blockIdx.y * gridDim.x + blockIdx.x;
  const int swz = (flat & 7) * (nwg >> 3) + (flat >> 3);
  const int mb = (swz / gridDim.x) * 128;
  const int nb = (swz % gridDim.x) * 128;

  const int srow = tid >> 2, scb = (tid & 3) * 8;
  const size_t gA = (size_t)(mb + srow) * K + scb;
  const size_t gB = (size_t)(nb + srow) * K + scb;
  const int ldso = wid * 512;

  f32x4 acc[4][4];
  #pragma unroll
  for (int i = 0; i < 4; ++i)
    #pragma unroll
    for (int j = 0; j < 4; ++j) acc[i][j] = (f32x4){0.f, 0.f, 0.f, 0.f};

  auto stage = [&](int buf, int kt) {
    const size_t ko = (size_t)kt * 32;
    gload_lds16(A  + gA + ko,                  &As[buf][ldso]);
    gload_lds16(A  + gA + 64 * (size_t)K + ko, &As[buf][2048 + ldso]);
    gload_lds16(Bt + gB + ko,                  &Bs[buf][ldso]);
    gload_lds16(Bt + gB + 64 * (size_t)K + ko, &Bs[buf][2048 + ldso]);
  };

  const int ktn = K >> 5;
  stage(0, 0);
  stage(1, 1);

  int cur = 0;
  #pragma unroll 1
  for (int kt = 0; kt < ktn; ++kt) {
    if (kt + 2 < ktn) {
      int nbuf = cur + 2; if (nbuf >= 3) nbuf -= 3;
      stage(nbuf, kt + 2);
      asm volatile("s_waitcnt vmcnt(8)" ::: "memory");
    } else if (kt + 1 < ktn) {
      asm volatile("s_waitcnt vmcnt(4)" ::: "memory");
    } else {
      asm volatile("s_waitcnt vmcnt(0)" ::: "memory");
    }
    __builtin_amdgcn_sched_barrier(0);
    __builtin_amdgcn_s_barrier();
    bf16x8 af[4], bfv[4];
    #pragma unroll
    for (int m = 0; m < 4; ++m)
      af[m]  = *(const bf16x8*)&As[cur][(wr * 64 + m * 16 + lr) * 32 + lk * 8];
    #pragma unroll
    for (int n = 0; n < 4; ++n)
      bfv[n] = *(const bf16x8*)&Bs[cur][(wc * 64 + n * 16 + lr) * 32 + lk * 8];
    #pragma unroll
    for (int m = 0; m < 4; ++m)
      #pragma unroll
      for (int n = 0; n < 4; ++n)
        acc[m][n] = __builtin_amdgcn_mfma_f32_16x16x32_bf16(af[m], bfv[n], acc[m][n], 0, 0, 0);
    __builtin_amdgcn_s_barrier();
    ++cur; if (cur == 3) cur = 0;
  }

  const int r0 = mb + wr * 64, c0 = nb + wc * 64;
  #pragma unroll
  for (int m = 0; m < 4; ++m) {
    #pragma unroll
    for (int n = 0; n < 4; ++n) {
      int col = c0 + n * 16 + lr;
      float bb = b0[col];
      #pragma unroll
      for (int r = 0; r < 4; ++r) {
        int row = r0 + m * 16 + lk * 4 + r;
        Cout[(size_t)row * N + col] = acc[m][n][r] + bb;
      }
    }
  }
}

// ---------------- merged RoPE + V-transpose (one launch) ----------------
// bid < nrope: RoPE rows (q pre-scaled by 1/sqrt(D)); else V transpose tiles.
__global__ void k_rv(const unsigned short* __restrict__ qkv,
                     unsigned short* __restrict__ qr,
                     unsigned short* __restrict__ kr,
                     unsigned short* __restrict__ vt,
                     int S, int H, int nrope) {
  const int bid = blockIdx.x;
  if (bid < nrope) {
    int R = bid * 4 + (threadIdx.x >> 6);
    int lane = threadIdx.x & 63;
    int per_b = S * (H + 1);
    int b = R / per_b;
    int rem = R - b * per_b;
    int s = rem / (H + 1);
    int j = rem - s * (H + 1);
    const unsigned short* src = qkv + (size_t)(b * S + s) * 2304 + (j < H ? j * 128 : 2048);
    float x1 = b2f(src[lane]);
    float x2 = b2f(src[lane + 64]);
    float invf = expf(-(float)lane * (9.210340371976184f / 64.0f));
    float ang = (float)s * invf;
    float c = cosf(ang), sn = sinf(ang);
    float o1 = x1 * c - x2 * sn;
    float o2 = x1 * sn + x2 * c;
    unsigned short* dst;
    if (j < H) {
      const float scale = 0.08838834764831845f;
      o1 *= scale; o2 *= scale;
      dst = qr + ((size_t)(b * H + j) * S + s) * 128;
    } else {
      dst = kr + ((size_t)(b * S) + s) * 128;
    }
    dst[lane]      = f2b(o1);
    dst[lane + 64] = f2b(o2);
    return;
  }
  // V transpose: vid in [0, 64*4*2)
  __shared__ unsigned short tile[32][33];
  int vid = bid - nrope;
  int b  = vid >> 8;                 // 0..1
  int s0 = (vid & 63) * 32;          // 0..2016
  int d0 = ((vid >> 6) & 3) * 32;    // 0..96
  int tx = threadIdx.x & 31, ty = threadIdx.x >> 5;
  for (int yy = ty; yy < 32; yy += 8)
    tile[yy][tx] = qkv[(size_t)(b * S + s0 + yy) * 2304 + 2176 + d0 + tx];
  __syncthreads();
  for (int yy = ty; yy < 32; yy += 8)
    vt[((size_t)b * 128 + d0 + yy) * S + s0 + tx] = tile[tx][yy];
}

// ---------------- causal flash attention (r15 verified: balanced split + reuse) ----------------
__global__ __launch_bounds__(256, 2)
void k_attn(const unsigned short* __restrict__ qr,
            const unsigned short* __restrict__ kr,
            const unsigned short* __restrict__ vt,
            unsigned short* __restrict__ attn_out,
            unsigned short* __restrict__ pscr,
            float* __restrict__ lscr,
            int S, int H) {
  const int flat = blockIdx.x + 16 * blockIdx.y + 256 * blockIdx.z;
  const int half = flat >> 8;
  const int p    = flat & 7;
  const int h    = (flat >> 3) & 15;
  const int b    = (flat >> 7) & 1;
  const int qtA = 8 + p, qtB = 7 - p;
  const int qb0A = qtA * 128, qb0B = qtB * 128;
  const int nA = 2 * qtA + 2;
  const int pg = (b * H + h) * 8 + p;

  const int tid = threadIdx.x, wid = tid >> 6, lane = tid & 63;
  const int lr = lane & 15, lk = lane >> 4;

  __shared__ unsigned short Kt[2][64 * 128];
  __shared__ unsigned short Vt[2][128 * 64];

  const char* kbyte = (const char*)(kr + (size_t)b * S * 128);
  const char* vbyte = (const char*)(vt + (size_t)b * 128 * S);
  const size_t vrow_bytes = (size_t)S * 2;

  bf16x8 aq[2][4];
  auto loadQ = [&](int qb0) {
    #pragma unroll
    for (int g = 0; g < 2; ++g) {
      const unsigned short* qptr = qr + ((size_t)(b * H + h) * S + (qb0 + wid * 32 + g * 16 + lr)) * 128;
      #pragma unroll
      for (int kk = 0; kk < 4; ++kk) aq[g][kk] = *(const bf16x8*)(qptr + kk * 32 + lk * 8);
    }
  };

  f32x4 acc[2][8];
  float ls[2];
  auto resetAcc = [&]() {
    #pragma unroll
    for (int g = 0; g < 2; ++g) {
      ls[g] = 0.f;
      #pragma unroll
      for (int t = 0; t < 8; ++t) acc[g][t] = (f32x4){0.f, 0.f, 0.f, 0.f};
    }
  };

  const int vsw = ((lr & 3) | ((lr >> 1) & 4)) << 4;
  int krow_[4], ksw_[4];
  #pragma unroll
  for (int m = 0; m < 4; ++m) {
    int row = ((m >> 1) << 5) + ((m & 1) << 2) + ((lr >> 2) << 3) + (lr & 3);
    krow_[m] = row;
    ksw_[m] = ((row & 3) | ((row >> 1) & 4)) << 4;
  }

  auto stage = [&](int buf, int kb) {
    const char* kg = kbyte + (size_t)kb * 256;
    #pragma unroll
    for (int r = 0; r < 4; ++r) {
      int row = (tid >> 4) + r * 16;
      int sw = ((row & 3) | ((row >> 1) & 4)) << 4;
      const char* src = kg + row * 256 + (((tid & 15) << 4) ^ sw);
      gload_lds16(src, (void*)((char*)&Kt[buf][0] + r * 4096 + wid * 1024));
    }
    const char* vg = vbyte + (size_t)kb * 2;
    #pragma unroll
    for (int r = 0; r < 4; ++r) {
      int d = (tid >> 3) + r * 32;
      int sw = ((d & 3) | ((d >> 1) & 4)) << 4;
      const char* src = vg + (size_t)d * vrow_bytes + (((tid & 7) << 4) ^ sw);
      gload_lds16(src, (void*)((char*)&Vt[buf][0] + r * 4096 + wid * 1024));
    }
  };

  auto itemKb = [&](int j, int& which) -> int {
    int idx = half * 17 + j;
    if (idx < nA) { which = 0; return idx * 64; }
    which = 1; return (idx - nA) * 64;
  };

  auto flushA = [&]() {
    #pragma unroll
    for (int g = 0; g < 2; ++g) {
      float v = ls[g];
      v += __shfl_xor(v, 16);
      v += __shfl_xor(v, 32);
      if (lk == 0) lscr[((size_t)pg * 2 + half) * 128 + wid * 32 + g * 16 + lr] = v;
      #pragma unroll
      for (int t = 0; t < 8; ++t)
        #pragma unroll
        for (int r = 0; r < 4; ++r) {
          int row = wid * 32 + g * 16 + lk * 4 + r;
          pscr[((size_t)pg * 2 + half) * 16384 + row * 128 + t * 16 + lr] = f2b(acc[g][t][r]);
        }
    }
  };

  auto computeTile = [&](int cur, int kb, int qb0cur) {
    const int qw = qb0cur + wid * 32;
    if (kb > qw + 31) return;
    const unsigned short* Kc = &Kt[cur][0];
    const unsigned short* Vc = &Vt[cur][0];
    f32x4 s4[2][4];
    #pragma unroll
    for (int g = 0; g < 2; ++g)
      #pragma unroll
      for (int m = 0; m < 4; ++m) s4[g][m] = (f32x4){0.f, 0.f, 0.f, 0.f};
    __builtin_amdgcn_s_setprio(1);
    #pragma unroll
    for (int kk = 0; kk < 4; ++kk) {
      bf16x8 kfk[4];
      #pragma unroll
      for (int m = 0; m < 4; ++m)
        kfk[m] = *(const bf16x8*)((const char*)Kc + krow_[m] * 256 + ((kk * 64 + lk * 16) ^ ksw_[m]));
      #pragma unroll
      for (int m = 0; m < 4; ++m) {
        s4[0][m] = __builtin_amdgcn_mfma_f32_16x16x32_bf16(kfk[m], aq[0][kk], s4[0][m], 0, 0, 0);
        s4[1][m] = __builtin_amdgcn_mfma_f32_16x16x32_bf16(kfk[m], aq[1][kk], s4[1][m], 0, 0, 0);
      }
    }
    __builtin_amdgcn_s_setprio(0);
    bf16x8 pa[2][2];
    #pragma unroll
    for (int g = 0; g < 2; ++g) {
      const int rowq = qw + g * 16 + lr;
      const bool domask = (kb + 64) > (qw + g * 16);
      uint2 pk[4];
      #pragma unroll
      for (int m = 0; m < 4; ++m) {
        const int kb_m = kb + ((m >> 1) << 5) + ((m & 1) << 2) + lk * 8;
        float pv[4];
        #pragma unroll
        for (int r = 0; r < 4; ++r) {
          float v = __expf(s4[g][m][r]);
          if (domask && (kb_m + r) > rowq) v = 0.f;
          pv[r] = v;
          ls[g] += v;
        }
        pk[m].x = pkcvt(pv[0], pv[1]);
        pk[m].y = pkcvt(pv[2], pv[3]);
      }
      uint4 ua, ub;
      ua.x = pk[0].x; ua.y = pk[0].y; ua.z = pk[1].x; ua.w = pk[1].y;
      ub.x = pk[2].x; ub.y = pk[2].y; ub.z = pk[3].x; ub.w = pk[3].y;
      pa[g][0] = __builtin_bit_cast(bf16x8, ua);
      pa[g][1] = __builtin_bit_cast(bf16x8, ub);
    }
    __builtin_amdgcn_s_setprio(1);
    #pragma unroll
    for (int t = 0; t < 8; ++t) {
      const char* vl = (const char*)(Vc + (t * 16 + lr) * 64);
      bf16x8 bv0 = *(const bf16x8*)(vl + ((lk * 16) ^ vsw));
      bf16x8 bv1 = *(const bf16x8*)(vl + ((64 + lk * 16) ^ vsw));
      acc[0][t] = __builtin_amdgcn_mfma_f32_16x16x32_bf16(pa[0][0], bv0, acc[0][t], 0, 0, 0);
      acc[1][t] = __builtin_amdgcn_mfma_f32_16x16x32_bf16(pa[1][0], bv0, acc[1][t], 0, 0, 0);
      acc[0][t] = __builtin_amdgcn_mfma_f32_16x16x32_bf16(pa[0][1], bv1, acc[0][t], 0, 0, 0);
      acc[1][t] = __builtin_amdgcn_mfma_f32_16x16x32_bf16(pa[1][1], bv1, acc[1][t], 0, 0, 0);
    }
    __builtin_amdgcn_s_setprio(0);
  };

  loadQ(qb0A);
  resetAcc();
  int curTile = 0, qb0cur = qb0A;

  {
    int wh0;
    stage(0, itemKb(0, wh0));
  }
  int cur = 0;
  #pragma unroll 1
  for (int j = 0; j < 17; ++j) {
    if (j + 1 < 17) {
      int whn;
      stage(cur ^ 1, itemKb(j + 1, whn));
      asm volatile("s_waitcnt vmcnt(8)" ::: "memory");
    } else {
      asm volatile("s_waitcnt vmcnt(0)" ::: "memory");
    }
    __builtin_amdgcn_sched_barrier(0);
    __builtin_amdgcn_s_barrier();
    int wh;
    const int kb = itemKb(j, wh);
    if (wh != curTile) {
      flushA();
      resetAcc();
      loadQ(qb0B);
      curTile = 1;
      qb0cur = qb0B;
    }
    computeTile(cur, kb, qb0cur);
    __builtin_amdgcn_s_barrier();
    cur ^= 1;
  }

  if (half == 0) {
    flushA();
  } else {
    #pragma unroll
    for (int g = 0; g < 2; ++g) {
      float v = ls[g];
      v += __shfl_xor(v, 16);
      v += __shfl_xor(v, 32);
      float rl[4];
      #pragma unroll
      for (int r = 0; r < 4; ++r) rl[r] = 1.0f / __shfl(v, lk * 4 + r);
      #pragma unroll
      for (int t = 0; t < 8; ++t) {
        #pragma unroll
        for (int r = 0; r < 4; ++r) {
          int srow = qb0B + wid * 32 + g * 16 + lk * 4 + r;
          float o = acc[g][t][r] * rl[r];
          attn_out[((size_t)(b * S) + srow) * 2048 + h * 128 + t * 16 + lr] = f2b(o);
        }
      }
    }
  }
}

// ---------------- combine A partials ----------------
__global__ void k_combine(const unsigned short* __restrict__ pscr,
                          const float* __restrict__ lscr,
                          unsigned short* __restrict__ attn_out, int S, int H) {
  const int p = blockIdx.x, h = blockIdx.y, b = blockIdx.z;
  const int pg = (b * H + h) * 8 + p;
  const int qb0A = (8 + p) * 128;
  const int tid = threadIdx.x;
  const unsigned short* p0 = pscr + (size_t)pg * 2 * 16384;
  const unsigned short* p1 = p0 + 16384;
  const float* l0 = lscr + (size_t)pg * 2 * 128;
  const float* l1 = l0 + 128;
  #pragma unroll
  for (int it = 0; it < 8; ++it) {
    int row = it * 16 + (tid >> 4);
    int col = (tid & 15) * 8;
    float rl = 1.0f / (l0[row] + l1[row]);
    ushort4 a = *(const ushort4*)(p0 + row * 128 + col);
    ushort4 c = *(const ushort4*)(p1 + row * 128 + col);
    ushort4 a2 = *(const ushort4*)(p0 + row * 128 + col + 4);
    ushort4 c2 = *(const ushort4*)(p1 + row * 128 + col + 4);
    ushort4 o1, o2;
    o1.x = f2b((b2f(a.x) + b2f(c.x)) * rl);
    o1.y = f2b((b2f(a.y) + b2f(c.y)) * rl);
    o1.z = f2b((b2f(a.z) + b2f(c.z)) * rl);
    o1.w = f2b((b2f(a.w) + b2f(c.w)) * rl);
    o2.x = f2b((b2f(a2.x) + b2f(c2.x)) * rl);
    o2.y = f2b((b2f(a2.y) + b2f(c2.y)) * rl);
    o2.z = f2b((b2f(a2.z) + b2f(c2.z)) * rl);
    o2.w = f2b((b2f(a2.w) + b2f(c2.w)) * rl);
    unsigned short* dst = attn_out + ((size_t)(b * S) + qb0A + row) * 2048 + h * 128 + col;
    *(ushort4*)dst = o1;
    *(ushort4*)(dst + 4) = o2;
  }
}

// ---------------- launch ----------------
extern "C" void kernel_launch(void* const* d_in, const int* in_sizes, int n_in,
                              void* d_out, int out_size, void* d_ws, size_t ws_size,
                              hipStream_t stream) {
  const float* x  = (const float*)d_in[0];
  const float* Wq = (const float*)d_in[1];
  const float* bq = (const float*)d_in[2];
  const float* Wk = (const float*)d_in[3];
  const float* bk = (const float*)d_in[4];
  const float* Wv = (const float*)d_in[5];
  const float* bv = (const float*)d_in[6];
  const float* Wo = (const float*)d_in[7];
  const float* bo = (const float*)d_in[8];

  const int B = 2, S = 2048, E = 2048, H = 16, D = 128;
  const int M = B * S;             // 4096
  const int Nqkv = H * D + 2 * D;  // 2304

  char* w = (char*)d_ws;
  unsigned short* xb    = (unsigned short*)w;
  unsigned short* WqkvT = (unsigned short*)(w + 16777216);
  unsigned short* qkv   = (unsigned short*)(w + 16777216 + 9437184);
  unsigned short* qr    = (unsigned short*)(w + 16777216 + 9437184 + 18874368);
  unsigned short* kr    = qr + (size_t)B * H * S * D;
  unsigned short* vtb   = kr + (size_t)B * S * D;
  float*          cbias = (float*)(vtb + (size_t)B * S * D);
  unsigned short* WoT   = (unsigned short*)(cbias + 4096);
  unsigned short* attn_out = xb;
  unsigned short* pscr  = qkv;
  float*          lscr  = (float*)WqkvT;

  const int nrope = B * S * (H + 1) / 4;   // 8704
  k_prep<<<dim3(Nqkv / 32, E / 32, 3), 256, 0, stream>>>(Wq, Wk, Wv, Wo, x, xb, WqkvT, WoT, M * E / 4);
  k_gemm96<1><<<dim3(Nqkv / 96, M / 128), 256, 0, stream>>>(xb, WqkvT, bq, bk, bv, qkv, M, Nqkv, E);
  k_rv<<<dim3(nrope + 512), 256, 0, stream>>>(qkv, qr, kr, vtb, S, H, nrope);
  k_attn<<<dim3(16, 16, 2), 256, 0, stream>>>(qr, kr, vtb, attn_out, pscr, lscr, S, H);
  k_combine<<<dim3(8, H, B), 256, 0, stream>>>(pscr, lscr, attn_out, S, H);
  k_gemm2<<<dim3(E / 128, M / 128), 256, 0, stream>>>(attn_out, WoT, bo, (float*)d_out, M, E, H * D);
}